// Round 3
// baseline (1089.448 us; speedup 1.0000x reference)
//
#include <hip/hip_runtime.h>

#define B_ 8
#define L_ 2048
#define D_ 64
#define K_ 40
#define NU_ 32
#define T_ 2047   // L-1
#define NSPLIT 8

// ---- workspace layout (in floats) ----
#define XT_OFF   0
#define XT_SZ    (B_*L_*NU_)                 // 524288
#define HH_OFF   (XT_OFF + XT_SZ)
#define HH_SZ    (B_*K_*T_*NU_)              // 20,961,280
#define HTHP_OFF (HH_OFF + HH_SZ)
#define HTHP_SZ  (NSPLIT*B_*K_*NU_*NU_)      // 2,621,440
#define HTXP_OFF (HTHP_OFF + HTHP_SZ)
#define HTXP_SZ  (NSPLIT*B_*K_*NU_*D_)      // 5,242,880
#define SH_OFF   (HTXP_OFF + HTXP_SZ)
#define SH_SZ    (B_*K_*NU_)
#define SX_OFF   (SH_OFF + SH_SZ)
#define SX_SZ    (B_*K_)

#if __has_builtin(__builtin_amdgcn_exp2f)
#define EXP2F(x) __builtin_amdgcn_exp2f(x)
#else
#define EXP2F(x) __expf((x)*0.6931471805599453f)
#endif
#if __has_builtin(__builtin_amdgcn_rcpf)
#define RCPF(x) __builtin_amdgcn_rcpf(x)
#else
#define RCPF(x) (1.0f/(x))
#endif

// ================= K1: xt = x @ W_in  (B*L rows, 64 -> 32) =================
__global__ __launch_bounds__(256) void k1_xt(const float* __restrict__ x,
                                             const float* __restrict__ Win,
                                             float* __restrict__ xt)
{
    __shared__ float Ws[D_*NU_];
    for (int i = threadIdx.x; i < D_*NU_; i += 256) Ws[i] = Win[i];
    __syncthreads();
    int gid = blockIdx.x*256 + threadIdx.x;       // < 524288
    int m   = gid & 31;
    int row = gid >> 5;
    const float4* xr = (const float4*)(x + (size_t)row * 64);
    float s = 0.f;
#pragma unroll
    for (int q = 0; q < 16; ++q) {
        float4 v = xr[q];
        s = fmaf(v.x, Ws[(q*4+0)*32+m], s);
        s = fmaf(v.y, Ws[(q*4+1)*32+m], s);
        s = fmaf(v.z, Ws[(q*4+2)*32+m], s);
        s = fmaf(v.w, Ws[(q*4+3)*32+m], s);
    }
    xt[gid] = s;
}

// ================= K2: delay-decomposed recurrence ==========================
// one 64-lane wave per (b, r, chain c). h_r(t) = tanh(xt(t) + h_r(t-(r+1)) @ Wr)
// Lane m (= l&31; halves redundant) owns output m: full 32-term dot.
// h-broadcast via v_readlane (VALU pipe, no LDS round trip on the serial chain).
__global__ __launch_bounds__(64) void k2_rec(const float* __restrict__ ws_xt,
                                             const float* __restrict__ Wres,
                                             const float* __restrict__ radii,
                                             float* __restrict__ hh)
{
    const int l = threadIdx.x;
    const int m = l & 31;
    int e = blockIdx.x % 820;
    int b = blockIdx.x / 820;
    int r = 0, base = 0;
    while (e >= base + r + 1) { base += r + 1; ++r; }
    const int cc     = e - base;
    const int stride = r + 1;
    const float rad  = radii[r];
    // lane m needs column m of Wr: w[n] = Wr[r][n][m] * rad, all n
    float w[32];
#pragma unroll
    for (int n = 0; n < 32; ++n)
        w[n] = Wres[r*1024 + n*32 + m] * rad;

    const float* xt = ws_xt + (size_t)b * L_ * NU_;
    float* hrow = hh + ((size_t)(b*K_ + r)) * T_ * NU_;

    const int nsteps = (T_ - 1 - cc) / stride + 1;
    const int adv = stride * NU_;
    // 3-deep xt prefetch; reads past xt's tail land in allocated ws (hh) and
    // are mathematically dead (rotation discards them), so no clamps needed.
    const float* xp = xt + (size_t)cc * NU_ + m;
    float xv0 = xp[0];
    float xv1 = xp[adv];
    float xv2 = xp[2*adv];
    const float* xp3 = xp + 3*(size_t)adv;
    float* hp = hrow + (size_t)cc * NU_ + l;   // valid store target for l<32

    int hb = 0;  // h = 0 initial state (bits)
#pragma unroll 2
    for (int sstep = 0; sstep < nsteps; ++sstep) {
        float xv3 = *xp3;                       // prefetch t+3*stride
        xp3 += adv;
        float a0 = xv0, a1 = 0.f, a2 = 0.f, a3 = 0.f;
#define RL(N, ACC) { int g_ = __builtin_amdgcn_readlane(hb, N); \
                     ACC = fmaf(w[N], __int_as_float(g_), ACC); }
        RL(0,a0)  RL(1,a1)  RL(2,a2)  RL(3,a3)
        RL(4,a0)  RL(5,a1)  RL(6,a2)  RL(7,a3)
        RL(8,a0)  RL(9,a1)  RL(10,a2) RL(11,a3)
        RL(12,a0) RL(13,a1) RL(14,a2) RL(15,a3)
        RL(16,a0) RL(17,a1) RL(18,a2) RL(19,a3)
        RL(20,a0) RL(21,a1) RL(22,a2) RL(23,a3)
        RL(24,a0) RL(25,a1) RL(26,a2) RL(27,a3)
        RL(28,a0) RL(29,a1) RL(30,a2) RL(31,a3)
#undef RL
        float s = (a0 + a1) + (a2 + a3);
        // tanh(s) = 1 - 2/(exp2(2*log2e*s)+1); self-saturating in fp32
        float ex = EXP2F(s * 2.8853900817779268f);
        float hn = fmaf(-2.f, RCPF(ex + 1.f), 1.f);
        if (l < 32) *hp = hn;
        hp += adv;
        hb = __float_as_int(hn);
        xv0 = xv1; xv1 = xv2; xv2 = xv3;
    }
}

// ================= K3: HtH / HtX partials = H^T [H|X] ======================
// grid (split s, k, b); 64 threads; 48 compute an 8x8 tile of the 32x96 output
__global__ __launch_bounds__(64) void k3_gemm(const float* __restrict__ hh,
                                              const float* __restrict__ x,
                                              float* __restrict__ htHp,
                                              float* __restrict__ htXp,
                                              float* __restrict__ sH,
                                              float* __restrict__ sX)
{
    const int s  = blockIdx.x;
    const int k  = blockIdx.y;
    const int b  = blockIdx.z;
    const int l  = threadIdx.x;
    const int bk = b*K_ + k;
    const int Tk = T_ - k;                  // valid rows
    __shared__ __align__(16) float P[32][96];
    const int tidn = l / 12;                // 0..3  (for l<48)
    const int tidc = l % 12;                // 0..11

    float acc[8][8];
#pragma unroll
    for (int i = 0; i < 8; ++i)
#pragma unroll
        for (int j = 0; j < 8; ++j) acc[i][j] = 0.f;
    float bsum[8];
#pragma unroll
    for (int j = 0; j < 8; ++j) bsum[j] = 0.f;

    const float* hrow = hh + (size_t)bk * T_ * NU_;
    const float* xrow = x + (size_t)b * L_ * D_ + (size_t)(k+1) * D_;  // Xm row tt = x[b, tt+k+1]

    for (int ch = s*8; ch < s*8 + 8; ++ch) {
        const int t0 = ch*32;
        // ---- stage 32 rows x [H(32) | X(64)] ----
#pragma unroll
        for (int rd = 0; rd < 12; ++rd) {
            int slot = rd*64 + l;
            int row  = slot / 24;
            int q    = slot % 24;
            int tt   = t0 + row;
            float4 v = make_float4(0.f, 0.f, 0.f, 0.f);
            if (tt < Tk) {
                if (q < 8) v = *(const float4*)(hrow + (size_t)tt*32 + q*4);
                else       v = *(const float4*)(xrow + (size_t)tt*64 + (q-8)*4);
            }
            *(float4*)&P[row][q*4] = v;
        }
        __syncthreads();
        if (l < 48) {
#pragma unroll 4
            for (int tt = 0; tt < 32; ++tt) {
                const float* pr = &P[tt][0];
                float4 A0 = *(const float4*)(pr + tidn*8);
                float4 A1 = *(const float4*)(pr + tidn*8 + 4);
                float4 B0 = *(const float4*)(pr + tidc*8);
                float4 B1 = *(const float4*)(pr + tidc*8 + 4);
                float av[8] = {A0.x,A0.y,A0.z,A0.w,A1.x,A1.y,A1.z,A1.w};
                float bv[8] = {B0.x,B0.y,B0.z,B0.w,B1.x,B1.y,B1.z,B1.w};
#pragma unroll
                for (int i = 0; i < 8; ++i)
#pragma unroll
                    for (int j = 0; j < 8; ++j)
                        acc[i][j] = fmaf(av[i], bv[j], acc[i][j]);
#pragma unroll
                for (int j = 0; j < 8; ++j) bsum[j] += bv[j];  // column sums (free-ish)
            }
        }
        __syncthreads();
    }
    if (l < 48) {
        const int base_h = (s*(B_*K_) + bk)*NU_*NU_;
        const int base_x = (s*(B_*K_) + bk)*NU_*D_;
#pragma unroll
        for (int i = 0; i < 8; ++i) {
            int n = tidn*8 + i;
#pragma unroll
            for (int j = 0; j < 8; ++j) {
                int c = tidc*8 + j;
                if (c < 32) htHp[base_h + n*32 + c]      = acc[i][j];
                else        htXp[base_x + n*64 + (c-32)] = acc[i][j];
            }
        }
        if (tidn == 0) {                       // bsum identical across tidn
            if (tidc < 4) {
#pragma unroll
                for (int j = 0; j < 8; ++j)
                    atomicAdd(&sH[bk*32 + tidc*8 + j], bsum[j]);
            } else {
                float t = 0.f;
#pragma unroll
                for (int j = 0; j < 8; ++j) t += bsum[j];
                atomicAdd(&sX[bk], t);
            }
        }
    }
}

// ================= K4: Cholesky solve + features + f_norms =================
__global__ __launch_bounds__(64) void k4_solve(const float* __restrict__ htHp,
                                               const float* __restrict__ htXp,
                                               const float* __restrict__ sH,
                                               const float* __restrict__ sX,
                                               float* __restrict__ dout)
{
    const int k  = blockIdx.x;
    const int b  = blockIdx.y;
    const int bk = b*K_ + k;
    const int l  = threadIdx.x;
    __shared__ float As[32][33];
    // A = sum_s HtHp + REG*I   (REG = 1.0)
#pragma unroll
    for (int i = 0; i < 16; ++i) {
        int idx = i*64 + l;
        int row = idx >> 5, col = idx & 31;
        float v = (row == col) ? 1.0f : 0.0f;
        for (int s2 = 0; s2 < NSPLIT; ++s2)
            v += htHp[(size_t)(s2*(B_*K_) + bk)*1024 + idx];
        As[row][col] = v;
    }
    __syncthreads();
    // Cholesky (lower), lane i owns row i; single wave => lockstep
    for (int j = 0; j < 32; ++j) {
        float d   = sqrtf(As[j][j]);
        float inv = 1.0f / d;
        if (l == j) As[j][j] = d;
        if (l < 32 && l > j) As[l][j] *= inv;
        __syncthreads();
        if (l < 32 && l > j) {
            float lij = As[l][j];
            for (int c = j+1; c <= l; ++c)
                As[l][c] -= lij * As[c][j];
        }
        __syncthreads();
    }
    // solve for RHS column d = l (64 columns)
    float y[32];
#pragma unroll
    for (int i = 0; i < 32; ++i) {
        float v = 0.f;
        for (int s2 = 0; s2 < NSPLIT; ++s2)
            v += htXp[(size_t)(s2*(B_*K_) + bk)*2048 + i*64 + l];
        y[i] = v;
    }
#pragma unroll
    for (int i = 0; i < 32; ++i) {           // forward: L y' = y
        float v = y[i];
#pragma unroll
        for (int j = 0; j < i; ++j) v = fmaf(-As[i][j], y[j], v);
        y[i] = v / As[i][i];
    }
#pragma unroll
    for (int i = 31; i >= 0; --i) {          // backward: L^T w = y'
        float v = y[i];
#pragma unroll
        for (int j = i+1; j < 32; ++j) v = fmaf(-As[j][i], y[j], v);
        y[i] = v / As[i][i];
    }
    // features
    float* fout = dout + (size_t)bk * NU_ * D_;
#pragma unroll
    for (int n = 0; n < 32; ++n) fout[n*64 + l] = y[n];
    // f_norms[k] += sum_d sum_n sH[n]*W[n,d] - sX   (atomically over b)
    const float* sh = sH + bk*32;
    float part = 0.f;
#pragma unroll
    for (int n = 0; n < 32; ++n) part = fmaf(sh[n], y[n], part);
#pragma unroll
    for (int off = 32; off > 0; off >>= 1) part += __shfl_xor(part, off);
    if (l == 0) atomicAdd(dout + (size_t)(B_*K_*NU_*D_) + k, part - sX[bk]);
}

// ============================================================================
extern "C" void kernel_launch(void* const* d_in, const int* in_sizes, int n_in,
                              void* d_out, int out_size, void* d_ws, size_t ws_size,
                              hipStream_t stream)
{
    const float* x     = (const float*)d_in[0];
    const float* radii = (const float*)d_in[1];
    const float* Win   = (const float*)d_in[2];
    const float* Wres  = (const float*)d_in[3];
    float* ws   = (float*)d_ws;
    float* xt   = ws + XT_OFF;
    float* hh   = ws + HH_OFF;
    float* htHp = ws + HTHP_OFF;
    float* htXp = ws + HTXP_OFF;
    float* sH   = ws + SH_OFF;
    float* sX   = ws + SX_OFF;
    float* out  = (float*)d_out;

    hipMemsetAsync(sH, 0, (size_t)(SH_SZ + SX_SZ)*sizeof(float), stream);
    hipMemsetAsync(out + (size_t)B_*K_*NU_*D_, 0, K_*sizeof(float), stream);

    k1_xt <<<(B_*L_*NU_)/256, 256, 0, stream>>>(x, Win, xt);
    k2_rec<<<B_*820, 64, 0, stream>>>(xt, Wres, radii, hh);
    k3_gemm<<<dim3(NSPLIT, K_, B_), 64, 0, stream>>>(hh, x, htHp, htXp, sH, sX);
    k4_solve<<<dim3(K_, B_), 64, 0, stream>>>(htHp, htXp, sH, sX, out);
}

// Round 5
// 909.225 us; speedup vs baseline: 1.1982x; 1.1982x over previous
//
#include <hip/hip_runtime.h>

#define B_ 8
#define L_ 2048
#define D_ 64
#define K_ 40
#define NU_ 32
#define T_ 2047   // L-1
#define NSPLIT 8

// ---- workspace layout (in floats) ----
#define XT_OFF   0
#define XT_SZ    (B_*L_*NU_)                 // 524288
#define HH_OFF   (XT_OFF + XT_SZ)
#define HH_SZ    (B_*K_*T_*NU_)              // 20,961,280
#define HTHP_OFF (HH_OFF + HH_SZ)
#define HTHP_SZ  (NSPLIT*B_*K_*NU_*NU_)      // 2,621,440
#define HTXP_OFF (HTHP_OFF + HTHP_SZ)
#define HTXP_SZ  (NSPLIT*B_*K_*NU_*D_)      // 5,242,880
#define SH_OFF   (HTXP_OFF + HTXP_SZ)
#define SH_SZ    (B_*K_*NU_)
#define SX_OFF   (SH_OFF + SH_SZ)
#define SX_SZ    (B_*K_)

#if __has_builtin(__builtin_amdgcn_exp2f)
#define EXP2F(x) __builtin_amdgcn_exp2f(x)
#else
#define EXP2F(x) __expf((x)*0.6931471805599453f)
#endif
#if __has_builtin(__builtin_amdgcn_rcpf)
#define RCPF(x) __builtin_amdgcn_rcpf(x)
#else
#define RCPF(x) (1.0f/(x))
#endif

// ================= K1: xt = x @ W_in  (B*L rows, 64 -> 32) =================
__global__ __launch_bounds__(256) void k1_xt(const float* __restrict__ x,
                                             const float* __restrict__ Win,
                                             float* __restrict__ xt)
{
    __shared__ float Ws[D_*NU_];
    for (int i = threadIdx.x; i < D_*NU_; i += 256) Ws[i] = Win[i];
    __syncthreads();
    int gid = blockIdx.x*256 + threadIdx.x;       // < 524288
    int m   = gid & 31;
    int row = gid >> 5;
    const float4* xr = (const float4*)(x + (size_t)row * 64);
    float s = 0.f;
#pragma unroll
    for (int q = 0; q < 16; ++q) {
        float4 v = xr[q];
        s = fmaf(v.x, Ws[(q*4+0)*32+m], s);
        s = fmaf(v.y, Ws[(q*4+1)*32+m], s);
        s = fmaf(v.z, Ws[(q*4+2)*32+m], s);
        s = fmaf(v.w, Ws[(q*4+3)*32+m], s);
    }
    xt[gid] = s;
}

// ================= K2: delay-decomposed recurrence ==========================
// one 64-lane wave per (b, r, chain c). h_r(t) = tanh(xt(t) + h_r(t-(r+1)) @ Wr)
// Lane m (= l&31; halves redundant) owns output m: full 32-term dot via
// v_readlane broadcasts. ALL per-lane state is in individually-named scalars
// (w0..w31, xa*/xb*, sa*/sb*) so the compiler cannot demote to scratch
// (round-3 counters showed VGPR_Count=24 with float w[32] => spilled).
// 8-step chunks: loads for chunk c+1 issue first, compute runs on registers,
// stores of chunk c go last; store-data regs rewritten 2 chunks later.
#define RLV(N) __int_as_float(__builtin_amdgcn_readlane(hb, N))

#define STEP(XV, SD) { \
    float a0 = XV, a1 = 0.f, a2 = 0.f, a3 = 0.f; \
    a0 = fmaf(w0,  RLV(0),  a0); a1 = fmaf(w1,  RLV(1),  a1); \
    a2 = fmaf(w2,  RLV(2),  a2); a3 = fmaf(w3,  RLV(3),  a3); \
    a0 = fmaf(w4,  RLV(4),  a0); a1 = fmaf(w5,  RLV(5),  a1); \
    a2 = fmaf(w6,  RLV(6),  a2); a3 = fmaf(w7,  RLV(7),  a3); \
    a0 = fmaf(w8,  RLV(8),  a0); a1 = fmaf(w9,  RLV(9),  a1); \
    a2 = fmaf(w10, RLV(10), a2); a3 = fmaf(w11, RLV(11), a3); \
    a0 = fmaf(w12, RLV(12), a0); a1 = fmaf(w13, RLV(13), a1); \
    a2 = fmaf(w14, RLV(14), a2); a3 = fmaf(w15, RLV(15), a3); \
    a0 = fmaf(w16, RLV(16), a0); a1 = fmaf(w17, RLV(17), a1); \
    a2 = fmaf(w18, RLV(18), a2); a3 = fmaf(w19, RLV(19), a3); \
    a0 = fmaf(w20, RLV(20), a0); a1 = fmaf(w21, RLV(21), a1); \
    a2 = fmaf(w22, RLV(22), a2); a3 = fmaf(w23, RLV(23), a3); \
    a0 = fmaf(w24, RLV(24), a0); a1 = fmaf(w25, RLV(25), a1); \
    a2 = fmaf(w26, RLV(26), a2); a3 = fmaf(w27, RLV(27), a3); \
    a0 = fmaf(w28, RLV(28), a0); a1 = fmaf(w29, RLV(29), a1); \
    a2 = fmaf(w30, RLV(30), a2); a3 = fmaf(w31, RLV(31), a3); \
    float sdot = (a0 + a1) + (a2 + a3); \
    float ex = EXP2F(sdot * 2.8853900817779268f); \
    SD = fmaf(-2.f, RCPF(ex + 1.f), 1.f); \
    hb = __float_as_int(SD); }

#define CHUNK(XC, XN, ST) { \
    XN##0 = xnp[0];               XN##1 = xnp[(size_t)1*adv]; \
    XN##2 = xnp[(size_t)2*adv];   XN##3 = xnp[(size_t)3*adv]; \
    XN##4 = xnp[(size_t)4*adv];   XN##5 = xnp[(size_t)5*adv]; \
    XN##6 = xnp[(size_t)6*adv];   XN##7 = xnp[(size_t)7*adv]; \
    xnp += 8*(size_t)adv; \
    STEP(XC##0, ST##0) STEP(XC##1, ST##1) STEP(XC##2, ST##2) STEP(XC##3, ST##3) \
    STEP(XC##4, ST##4) STEP(XC##5, ST##5) STEP(XC##6, ST##6) STEP(XC##7, ST##7) \
    if (l < 32) { \
        if (srem > 0) hq[0]             = ST##0; \
        if (srem > 1) hq[(size_t)1*adv] = ST##1; \
        if (srem > 2) hq[(size_t)2*adv] = ST##2; \
        if (srem > 3) hq[(size_t)3*adv] = ST##3; \
        if (srem > 4) hq[(size_t)4*adv] = ST##4; \
        if (srem > 5) hq[(size_t)5*adv] = ST##5; \
        if (srem > 6) hq[(size_t)6*adv] = ST##6; \
        if (srem > 7) hq[(size_t)7*adv] = ST##7; \
    } \
    hq += 8*(size_t)adv; srem -= 8; }

__global__ __launch_bounds__(64, 2) void k2_rec(const float* __restrict__ ws_xt,
                                                const float* __restrict__ Wres,
                                                const float* __restrict__ radii,
                                                float* __restrict__ hh)
{
    const int l = threadIdx.x;
    const int m = l & 31;
    int e = blockIdx.x % 820;
    int b = blockIdx.x / 820;
    int r = 0, base = 0;
    while (e >= base + r + 1) { base += r + 1; ++r; }
    const int cc     = e - base;
    const int stride = r + 1;
    const float rad  = radii[r];
    // lane m needs column m of Wr: wN = Wr[r][N][m] * rad
    const float* Wp = Wres + r*1024 + m;
    float w0  = Wp[0*32]*rad,  w1  = Wp[1*32]*rad,  w2  = Wp[2*32]*rad,  w3  = Wp[3*32]*rad;
    float w4  = Wp[4*32]*rad,  w5  = Wp[5*32]*rad,  w6  = Wp[6*32]*rad,  w7  = Wp[7*32]*rad;
    float w8  = Wp[8*32]*rad,  w9  = Wp[9*32]*rad,  w10 = Wp[10*32]*rad, w11 = Wp[11*32]*rad;
    float w12 = Wp[12*32]*rad, w13 = Wp[13*32]*rad, w14 = Wp[14*32]*rad, w15 = Wp[15*32]*rad;
    float w16 = Wp[16*32]*rad, w17 = Wp[17*32]*rad, w18 = Wp[18*32]*rad, w19 = Wp[19*32]*rad;
    float w20 = Wp[20*32]*rad, w21 = Wp[21*32]*rad, w22 = Wp[22*32]*rad, w23 = Wp[23*32]*rad;
    float w24 = Wp[24*32]*rad, w25 = Wp[25*32]*rad, w26 = Wp[26*32]*rad, w27 = Wp[27*32]*rad;
    float w28 = Wp[28*32]*rad, w29 = Wp[29*32]*rad, w30 = Wp[30*32]*rad, w31 = Wp[31*32]*rad;

    const float* xt = ws_xt + (size_t)b * L_ * NU_;
    float* hrow = hh + ((size_t)(b*K_ + r)) * T_ * NU_;

    const int nsteps = (T_ - 1 - cc) / stride + 1;
    const int adv = stride * NU_;
    const float* xnp = xt + (size_t)cc * NU_ + m;
    float* hq = hrow + (size_t)cc * NU_ + m;

    // prologue: load chunk 0 into xa
    float xa0 = xnp[0],             xa1 = xnp[(size_t)1*adv],
          xa2 = xnp[(size_t)2*adv], xa3 = xnp[(size_t)3*adv],
          xa4 = xnp[(size_t)4*adv], xa5 = xnp[(size_t)5*adv],
          xa6 = xnp[(size_t)6*adv], xa7 = xnp[(size_t)7*adv];
    xnp += 8*(size_t)adv;
    float xb0=0,xb1=0,xb2=0,xb3=0,xb4=0,xb5=0,xb6=0,xb7=0;
    float sa0,sa1,sa2,sa3,sa4,sa5,sa6,sa7;
    float sb0,sb1,sb2,sb3,sb4,sb5,sb6,sb7;

    int hb = 0;  // h = 0 initial state (bits)
    int srem = nsteps;
    const int nchunks = (nsteps + 7) >> 3;
    int c = 0;
    for (; c + 2 <= nchunks; c += 2) {
        CHUNK(xa, xb, sa)
        CHUNK(xb, xa, sb)
    }
    if (c < nchunks) CHUNK(xa, xb, sa)
}

// ================= K3: HtH / HtX partials = H^T [H|X] ======================
// grid (split s, k, b); 64 threads; 48 compute an 8x8 tile of the 32x96 output
__global__ __launch_bounds__(64) void k3_gemm(const float* __restrict__ hh,
                                              const float* __restrict__ x,
                                              float* __restrict__ htHp,
                                              float* __restrict__ htXp,
                                              float* __restrict__ sH,
                                              float* __restrict__ sX)
{
    const int s  = blockIdx.x;
    const int k  = blockIdx.y;
    const int b  = blockIdx.z;
    const int l  = threadIdx.x;
    const int bk = b*K_ + k;
    const int Tk = T_ - k;                  // valid rows
    __shared__ __align__(16) float P[32][96];
    const int tidn = l / 12;                // 0..3  (for l<48)
    const int tidc = l % 12;                // 0..11

    float acc[8][8];
#pragma unroll
    for (int i = 0; i < 8; ++i)
#pragma unroll
        for (int j = 0; j < 8; ++j) acc[i][j] = 0.f;
    float bsum[8];
#pragma unroll
    for (int j = 0; j < 8; ++j) bsum[j] = 0.f;

    const float* hrow = hh + (size_t)bk * T_ * NU_;
    const float* xrow = x + (size_t)b * L_ * D_ + (size_t)(k+1) * D_;  // Xm row tt = x[b, tt+k+1]

    for (int ch = s*8; ch < s*8 + 8; ++ch) {
        const int t0 = ch*32;
        // ---- stage 32 rows x [H(32) | X(64)] ----
#pragma unroll
        for (int rd = 0; rd < 12; ++rd) {
            int slot = rd*64 + l;
            int row  = slot / 24;
            int q    = slot % 24;
            int tt   = t0 + row;
            float4 v = make_float4(0.f, 0.f, 0.f, 0.f);
            if (tt < Tk) {
                if (q < 8) v = *(const float4*)(hrow + (size_t)tt*32 + q*4);
                else       v = *(const float4*)(xrow + (size_t)tt*64 + (q-8)*4);
            }
            *(float4*)&P[row][q*4] = v;
        }
        __syncthreads();
        if (l < 48) {
#pragma unroll 4
            for (int tt = 0; tt < 32; ++tt) {
                const float* pr = &P[tt][0];
                float4 A0 = *(const float4*)(pr + tidn*8);
                float4 A1 = *(const float4*)(pr + tidn*8 + 4);
                float4 B0 = *(const float4*)(pr + tidc*8);
                float4 B1 = *(const float4*)(pr + tidc*8 + 4);
                float av[8] = {A0.x,A0.y,A0.z,A0.w,A1.x,A1.y,A1.z,A1.w};
                float bv[8] = {B0.x,B0.y,B0.z,B0.w,B1.x,B1.y,B1.z,B1.w};
#pragma unroll
                for (int i = 0; i < 8; ++i)
#pragma unroll
                    for (int j = 0; j < 8; ++j)
                        acc[i][j] = fmaf(av[i], bv[j], acc[i][j]);
#pragma unroll
                for (int j = 0; j < 8; ++j) bsum[j] += bv[j];  // column sums (free-ish)
            }
        }
        __syncthreads();
    }
    if (l < 48) {
        const int base_h = (s*(B_*K_) + bk)*NU_*NU_;
        const int base_x = (s*(B_*K_) + bk)*NU_*D_;
#pragma unroll
        for (int i = 0; i < 8; ++i) {
            int n = tidn*8 + i;
#pragma unroll
            for (int j = 0; j < 8; ++j) {
                int c = tidc*8 + j;
                if (c < 32) htHp[base_h + n*32 + c]      = acc[i][j];
                else        htXp[base_x + n*64 + (c-32)] = acc[i][j];
            }
        }
        if (tidn == 0) {                       // bsum identical across tidn
            if (tidc < 4) {
#pragma unroll
                for (int j = 0; j < 8; ++j)
                    atomicAdd(&sH[bk*32 + tidc*8 + j], bsum[j]);
            } else {
                float t = 0.f;
#pragma unroll
                for (int j = 0; j < 8; ++j) t += bsum[j];
                atomicAdd(&sX[bk], t);
            }
        }
    }
}

// ================= K4: Cholesky solve + features + f_norms =================
__global__ __launch_bounds__(64) void k4_solve(const float* __restrict__ htHp,
                                               const float* __restrict__ htXp,
                                               const float* __restrict__ sH,
                                               const float* __restrict__ sX,
                                               float* __restrict__ dout)
{
    const int k  = blockIdx.x;
    const int b  = blockIdx.y;
    const int bk = b*K_ + k;
    const int l  = threadIdx.x;
    __shared__ float As[32][33];
    // A = sum_s HtHp + REG*I   (REG = 1.0)
#pragma unroll
    for (int i = 0; i < 16; ++i) {
        int idx = i*64 + l;
        int row = idx >> 5, col = idx & 31;
        float v = (row == col) ? 1.0f : 0.0f;
        for (int s2 = 0; s2 < NSPLIT; ++s2)
            v += htHp[(size_t)(s2*(B_*K_) + bk)*1024 + idx];
        As[row][col] = v;
    }
    __syncthreads();
    // Cholesky (lower), lane i owns row i; single wave => lockstep
    for (int j = 0; j < 32; ++j) {
        float d   = sqrtf(As[j][j]);
        float inv = 1.0f / d;
        if (l == j) As[j][j] = d;
        if (l < 32 && l > j) As[l][j] *= inv;
        __syncthreads();
        if (l < 32 && l > j) {
            float lij = As[l][j];
            for (int c = j+1; c <= l; ++c)
                As[l][c] -= lij * As[c][j];
        }
        __syncthreads();
    }
    // solve for RHS column d = l (64 columns)
    float y[32];
#pragma unroll
    for (int i = 0; i < 32; ++i) {
        float v = 0.f;
        for (int s2 = 0; s2 < NSPLIT; ++s2)
            v += htXp[(size_t)(s2*(B_*K_) + bk)*2048 + i*64 + l];
        y[i] = v;
    }
#pragma unroll
    for (int i = 0; i < 32; ++i) {           // forward: L y' = y
        float v = y[i];
#pragma unroll
        for (int j = 0; j < i; ++j) v = fmaf(-As[i][j], y[j], v);
        y[i] = v / As[i][i];
    }
#pragma unroll
    for (int i = 31; i >= 0; --i) {          // backward: L^T w = y'
        float v = y[i];
#pragma unroll
        for (int j = i+1; j < 32; ++j) v = fmaf(-As[j][i], y[j], v);
        y[i] = v / As[i][i];
    }
    // features
    float* fout = dout + (size_t)bk * NU_ * D_;
#pragma unroll
    for (int n = 0; n < 32; ++n) fout[n*64 + l] = y[n];
    // f_norms[k] += sum_d sum_n sH[n]*W[n,d] - sX   (atomically over b)
    const float* sh = sH + bk*32;
    float part = 0.f;
#pragma unroll
    for (int n = 0; n < 32; ++n) part = fmaf(sh[n], y[n], part);
#pragma unroll
    for (int off = 32; off > 0; off >>= 1) part += __shfl_xor(part, off);
    if (l == 0) atomicAdd(dout + (size_t)(B_*K_*NU_*D_) + k, part - sX[bk]);
}

// ============================================================================
extern "C" void kernel_launch(void* const* d_in, const int* in_sizes, int n_in,
                              void* d_out, int out_size, void* d_ws, size_t ws_size,
                              hipStream_t stream)
{
    const float* x     = (const float*)d_in[0];
    const float* radii = (const float*)d_in[1];
    const float* Win   = (const float*)d_in[2];
    const float* Wres  = (const float*)d_in[3];
    float* ws   = (float*)d_ws;
    float* xt   = ws + XT_OFF;
    float* hh   = ws + HH_OFF;
    float* htHp = ws + HTHP_OFF;
    float* htXp = ws + HTXP_OFF;
    float* sH   = ws + SH_OFF;
    float* sX   = ws + SX_OFF;
    float* out  = (float*)d_out;

    hipMemsetAsync(sH, 0, (size_t)(SH_SZ + SX_SZ)*sizeof(float), stream);
    hipMemsetAsync(out + (size_t)B_*K_*NU_*D_, 0, K_*sizeof(float), stream);

    k1_xt <<<(B_*L_*NU_)/256, 256, 0, stream>>>(x, Win, xt);
    k2_rec<<<B_*820, 64, 0, stream>>>(xt, Wres, radii, hh);
    k3_gemm<<<dim3(NSPLIT, K_, B_), 64, 0, stream>>>(hh, x, htHp, htXp, sH, sX);
    k4_solve<<<dim3(K_, B_), 64, 0, stream>>>(htHp, htXp, sH, sX, out);
}